// Round 3
// baseline (298.324 us; speedup 1.0000x reference)
//
#include <hip/hip_runtime.h>

#define NC 64
#define NF 128
#define NT 192           // NC + NF
#define B_TOTAL 65536
#define RPB 4            // rays (waves) per 256-thread block

#define NEAR_F 2.0f
#define STEP_F (4.0f / 63.0f)
#define INV_STEP (63.0f / 4.0f)

// One wave (64 lanes) per ray. All LDS state is wave-private, so we use
// wave-synchronous LDS (wave_barrier, no s_barrier): this avoids the
// compiler's s_waitcnt vmcnt(0) drain before s_barrier, letting the
// dens/col prefetch issued at kernel start stay in flight across the
// whole sort/search/scatter phase.
__global__ __launch_bounds__(256) void render_ray_kernel(
    const float* __restrict__ cw,    // [B,64]  coarse weights
    const float* __restrict__ u_in,  // [B,128] uniform samples
    const float* __restrict__ dens,  // [B,192] raw density
    const float* __restrict__ col,   // [B,192,3] raw color
    float* __restrict__ out)         // [B,3] color map
{
    const int wave = threadIdx.x >> 6;
    const int lane = threadIdx.x & 63;
    const int ray  = blockIdx.x * RPB + wave;

    __shared__ float s_cdf [RPB][64];    // cdf[0..62] used
    __shared__ float s_m   [RPB][200];   // merged sorted depths (192 + pad)
    __shared__ int   s_hist[RPB][64];    // histogram of fine merge-offsets g

    // ---- Prefetch everything global up front (latency overlaps the sort) ----
    const float wraw = cw[(size_t)ray * NC + lane];
    float x = u_in[(size_t)ray * NF + lane];
    float y = u_in[(size_t)ray * NF + 64 + lane];

    float4 dv = make_float4(0.f, 0.f, 0.f, 0.f);
    float4 c0 = dv, c1 = dv, c2 = dv;
    const int i0 = 4 * lane;             // composite: 4 samples/lane, lanes 0..47
    if (lane < 48) {
        dv = *reinterpret_cast<const float4*>(dens + (size_t)ray * NT + i0);
        const float4* cp4 = reinterpret_cast<const float4*>(col + (size_t)ray * NT * 3 + 3 * (size_t)i0);
        c0 = cp4[0]; c1 = cp4[1]; c2 = cp4[2];
    }

    // ---- Phase 1: weights -> pdf -> cdf (wave scan) ----
    const float wv = (lane >= 1 && lane <= 62) ? (wraw + 1e-5f) : 0.0f;
    float ssum = wv;
    #pragma unroll
    for (int off = 32; off; off >>= 1) ssum += __shfl_xor(ssum, off);
    const float pdf = __fdividef(wv, ssum);
    float scan = pdf;
    #pragma unroll
    for (int off = 1; off < 64; off <<= 1) {
        const float t = __shfl_up(scan, off);
        if (lane >= off) scan += t;
    }
    s_cdf[wave][lane]  = scan;   // scan[0]==0 because wv[0]==0
    s_hist[wave][lane] = 0;
    __builtin_amdgcn_wave_barrier();

    // ---- Phase 2: bitonic sort of the 128 u values (registers + shfl_xor) ----
    #pragma unroll
    for (int k = 2; k <= 128; k <<= 1) {
        #pragma unroll
        for (int j = k >> 1; j > 0; j >>= 1) {
            if (j == 64) {
                const float mn = fminf(x, y);
                const float mx = fmaxf(x, y);
                x = mn; y = mx;
            } else {
                const bool lower = (lane & j) == 0;
                const bool ascx  = (k >= 128) ? true : ((lane & k) == 0);
                const bool ascy  = (k >= 128) ? true
                                 : ((k == 64) ? false : ((lane & k) == 0));
                const float px = __shfl_xor(x, j);
                const float py = __shfl_xor(y, j);
                x = (ascx == lower) ? fminf(x, px) : fmaxf(x, px);
                y = (ascy == lower) ? fminf(y, py) : fmaxf(y, py);
            }
        }
    }

    // ---- Phase 3: inverse-CDF sample + arithmetic merge ----
    const float* __restrict__ cdfp = s_cdf[wave];
    auto sample = [&](float u) -> float {
        int l = 0, h = 62;
        while (l < h) {
            const int mid = (l + h) >> 1;
            if (cdfp[mid] <= u) l = mid + 1; else h = mid;
        }
        const int below = l - 1;
        const float cb = cdfp[below];
        const float ca = cdfp[l];
        float denom = ca - cb;
        if (denom < 1e-5f) denom = 1.0f;
        const float t = __fdividef(u - cb, denom);
        return NEAR_F + ((float)below + 0.5f + t) * STEP_F;
    };

    const float fx = sample(x);
    const float fy = sample(y);
    int gx = (int)floorf((fx - NEAR_F) * INV_STEP) + 1;
    int gy = (int)floorf((fy - NEAR_F) * INV_STEP) + 1;
    gx = min(max(gx, 1), 63);
    gy = min(max(gy, 1), 63);

    s_m[wave][lane + gx]      = fx;
    s_m[wave][lane + 64 + gy] = fy;
    atomicAdd(&s_hist[wave][gx], 1);
    atomicAdd(&s_hist[wave][gy], 1);
    __builtin_amdgcn_wave_barrier();

    int hsum = s_hist[wave][lane];
    #pragma unroll
    for (int off = 1; off < 64; off <<= 1) {
        const int t = __shfl_up(hsum, off);
        if (lane >= off) hsum += t;
    }
    s_m[wave][lane + hsum] = NEAR_F + (float)lane * STEP_F;
    __builtin_amdgcn_wave_barrier();

    // ---- Phase 4: composite, 4 consecutive samples per lane (lanes 0..47) ----
    const float* __restrict__ mp = s_m[wave];
    float f0 = 1.0f, f1 = 1.0f, f2 = 1.0f, f3 = 1.0f;
    if (lane < 48) {
        const float m0 = mp[i0], m1 = mp[i0 + 1], m2 = mp[i0 + 2], m3 = mp[i0 + 3];
        const float m4 = mp[(lane == 47) ? 191 : (i0 + 4)];
        const float d0 = m1 - m0;
        const float d1 = m2 - m1;
        const float d2 = m3 - m2;
        const float d3 = (lane == 47) ? 1e10f : (m4 - m3);
        f0 = 1.0f - (1.0f - __expf(-dv.x * d0)) + 1e-10f;
        f1 = 1.0f - (1.0f - __expf(-dv.y * d1)) + 1e-10f;
        f2 = 1.0f - (1.0f - __expf(-dv.z * d2)) + 1e-10f;
        f3 = 1.0f - (1.0f - __expf(-dv.w * d3)) + 1e-10f;
    }

    // multiplicative exclusive scan across lanes for transmittance
    float scanp = f0 * f1 * f2 * f3;
    #pragma unroll
    for (int off = 1; off < 64; off <<= 1) {
        const float t = __shfl_up(scanp, off);
        if (lane >= off) scanp *= t;
    }
    float T0 = __shfl_up(scanp, 1);
    if (lane == 0) T0 = 1.0f;
    const float T1 = T0 * f0;
    const float T2 = T1 * f1;
    const float T3 = T2 * f2;

    float ax = 0.f, ay = 0.f, az = 0.f;
    if (lane < 48) {
        const float w0 = T0 * (1.0f - f0 + 1e-10f);
        const float w1 = T1 * (1.0f - f1 + 1e-10f);
        const float w2 = T2 * (1.0f - f2 + 1e-10f);
        const float w3 = T3 * (1.0f - f3 + 1e-10f);
        // col regs: s0=(c0.x,c0.y,c0.z) s1=(c0.w,c1.x,c1.y) s2=(c1.z,c1.w,c2.x) s3=(c2.y,c2.z,c2.w)
        ax = w0 * c0.x + w1 * c0.w + w2 * c1.z + w3 * c2.y;
        ay = w0 * c0.y + w1 * c1.x + w2 * c1.w + w3 * c2.z;
        az = w0 * c0.z + w1 * c1.y + w2 * c2.x + w3 * c2.w;
    }

    #pragma unroll
    for (int off = 32; off; off >>= 1) {
        ax += __shfl_xor(ax, off);
        ay += __shfl_xor(ay, off);
        az += __shfl_xor(az, off);
    }
    if (lane < 3) {
        const float v = (lane == 0) ? ax : ((lane == 1) ? ay : az);
        out[(size_t)ray * 3 + lane] = v;
    }
}

extern "C" void kernel_launch(void* const* d_in, const int* in_sizes, int n_in,
                              void* d_out, int out_size, void* d_ws, size_t ws_size,
                              hipStream_t stream) {
    // inputs: 0 ray_origin (unused), 1 ray_direction (unused),
    //         2 coarse_depth_values (constant linspace — unused),
    //         3 coarse_weights, 4 u, 5 raw_density, 6 raw_color
    const float* cwts = (const float*)d_in[3];
    const float* u    = (const float*)d_in[4];
    const float* dens = (const float*)d_in[5];
    const float* col  = (const float*)d_in[6];
    float* out = (float*)d_out;

    dim3 grid(B_TOTAL / RPB);
    dim3 block(256);
    hipLaunchKernelGGL(render_ray_kernel, grid, block, 0, stream,
                       cwts, u, dens, col, out);
}

// Round 4
// 297.438 us; speedup vs baseline: 1.0030x; 1.0030x over previous
//
#include <hip/hip_runtime.h>

#define NC 64
#define NF 128
#define NT 192           // NC + NF
#define B_TOTAL 65536
#define RPB 4            // rays (waves) per 256-thread block

#define NEAR_F 2.0f
#define STEP_F (4.0f / 63.0f)
#define BUCK_SCALE 504.0f   // 32 buckets per coarse interval: 63*32/4
#define NBUCK 2016

// One wave (64 lanes) per ray; all LDS is wave-private (wave_barrier only).
// Sort-free: fine depths are placed by counting scatter over 2016 value
// buckets (32 per coarse interval), so merge offsets g=(bucket>>5)+1 are
// consistent with the bucket ranking -> slot map is a bijection on [0,192).
__global__ __launch_bounds__(256) void render_ray_kernel(
    const float* __restrict__ cw,    // [B,64]  coarse weights
    const float* __restrict__ u_in,  // [B,128] uniform samples
    const float* __restrict__ dens,  // [B,192] raw density
    const float* __restrict__ col,   // [B,192,3] raw color
    float* __restrict__ out)         // [B,3] color map
{
    const int wave = threadIdx.x >> 6;
    const int lane = threadIdx.x & 63;
    const int ray  = blockIdx.x * RPB + wave;

    __shared__ __align__(16) float          s_cdf[RPB][64];
    __shared__ __align__(16) unsigned int   s_bkt[RPB][512];   // 2048 B of uint8 counts
    __shared__ __align__(16) unsigned short s_dwp[RPB][512];   // excl fine-count prefix per dword
    __shared__ __align__(16) float          s_m  [RPB][200];   // merged sorted depths

    // ---- Prefetch all global data up front ----
    const float wraw = cw[(size_t)ray * NC + lane];
    const float x = u_in[(size_t)ray * NF + lane];
    const float y = u_in[(size_t)ray * NF + 64 + lane];

    float4 dv = make_float4(0.f, 0.f, 0.f, 0.f);
    float4 c0 = dv, c1 = dv, c2 = dv;
    const int i0 = 4 * lane;             // composite: 4 samples/lane, lanes 0..47
    if (lane < 48) {
        dv = *reinterpret_cast<const float4*>(dens + (size_t)ray * NT + i0);
        const float4* cp4 = reinterpret_cast<const float4*>(col + (size_t)ray * NT * 3 + 3 * (size_t)i0);
        c0 = cp4[0]; c1 = cp4[1]; c2 = cp4[2];
    }

    // ---- Clear bucket counts (2048 B/ray, 32 B/lane) ----
    const uint4 zz = make_uint4(0u, 0u, 0u, 0u);
    ((uint4*)&s_bkt[wave][0])[2 * lane]     = zz;
    ((uint4*)&s_bkt[wave][0])[2 * lane + 1] = zz;

    // ---- Phase 1: weights -> pdf -> cdf (wave scan) ----
    const float wv = (lane >= 1 && lane <= 62) ? (wraw + 1e-5f) : 0.0f;
    float ssum = wv;
    #pragma unroll
    for (int off = 32; off; off >>= 1) ssum += __shfl_xor(ssum, off);
    const float pdf = __fdividef(wv, ssum);
    float scan = pdf;
    #pragma unroll
    for (int off = 1; off < 64; off <<= 1) {
        const float t = __shfl_up(scan, off);
        if (lane >= off) scan += t;
    }
    s_cdf[wave][lane] = scan;   // scan[0]==0 because wv[0]==0
    __builtin_amdgcn_wave_barrier();

    // ---- Phase 2: inverse-CDF sample (binary search) + bucket scatter ----
    const float* __restrict__ cdfp = s_cdf[wave];
    auto sample = [&](float u) -> float {
        int l = 0, h = 62;
        while (l < h) {
            const int mid = (l + h) >> 1;
            if (cdfp[mid] <= u) l = mid + 1; else h = mid;
        }
        const int below = l - 1;
        const float cb = cdfp[below];
        const float ca = cdfp[l];
        float denom = ca - cb;
        if (denom < 1e-5f) denom = 1.0f;
        const float t = __fdividef(u - cb, denom);
        return NEAR_F + ((float)below + 0.5f + t) * STEP_F;
    };

    const float fx = sample(x);
    const float fy = sample(y);

    int b0 = (int)((fx - NEAR_F) * BUCK_SCALE);
    int b1 = (int)((fy - NEAR_F) * BUCK_SCALE);
    b0 = min(max(b0, 0), NBUCK - 1);
    b1 = min(max(b1, 0), NBUCK - 1);

    const unsigned sh0 = (unsigned)(b0 & 3) * 8u;
    const unsigned sh1 = (unsigned)(b1 & 3) * 8u;
    const unsigned old0 = atomicAdd(&s_bkt[wave][b0 >> 2], 1u << sh0);
    const unsigned old1 = atomicAdd(&s_bkt[wave][b1 >> 2], 1u << sh1);
    const int arr0 = (int)((old0 >> sh0) & 0xffu);
    const int arr1 = (int)((old1 >> sh1) & 0xffu);
    __builtin_amdgcn_wave_barrier();

    // ---- Phase 3: byte-count prefix scan over the 512 dwords ----
    const uint4 va = ((const uint4*)&s_bkt[wave][0])[2 * lane];
    const uint4 vb = ((const uint4*)&s_bkt[wave][0])[2 * lane + 1];
    const int p0 = 0;
    const int p1 = p0 + (int)((va.x * 0x01010101u) >> 24);
    const int p2 = p1 + (int)((va.y * 0x01010101u) >> 24);
    const int p3 = p2 + (int)((va.z * 0x01010101u) >> 24);
    const int p4 = p3 + (int)((va.w * 0x01010101u) >> 24);
    const int p5 = p4 + (int)((vb.x * 0x01010101u) >> 24);
    const int p6 = p5 + (int)((vb.y * 0x01010101u) >> 24);
    const int p7 = p6 + (int)((vb.z * 0x01010101u) >> 24);
    const int tot = p7 + (int)((vb.w * 0x01010101u) >> 24);

    int incl = tot;
    #pragma unroll
    for (int off = 1; off < 64; off <<= 1) {
        const int t = __shfl_up(incl, off);
        if (lane >= off) incl += t;
    }
    const int base = incl - tot;

    uint4 w;
    w.x = (unsigned)(base + p0) | ((unsigned)(base + p1) << 16);
    w.y = (unsigned)(base + p2) | ((unsigned)(base + p3) << 16);
    w.z = (unsigned)(base + p4) | ((unsigned)(base + p5) << 16);
    w.w = (unsigned)(base + p6) | ((unsigned)(base + p7) << 16);
    ((uint4*)&s_dwp[wave][0])[lane] = w;
    __builtin_amdgcn_wave_barrier();

    // ---- Phase 4: place fines and coarse into merged array ----
    {
        const int dw = b0 >> 2, bp = b0 & 3;
        const unsigned v = s_bkt[wave][dw];
        const unsigned mask = (1u << (8u * (unsigned)bp)) - 1u;
        const int bytepre = (int)(((v & mask) * 0x01010101u) >> 24);
        const int rank = (int)s_dwp[wave][dw] + bytepre + arr0;
        s_m[wave][rank + (b0 >> 5) + 1] = fx;
    }
    {
        const int dw = b1 >> 2, bp = b1 & 3;
        const unsigned v = s_bkt[wave][dw];
        const unsigned mask = (1u << (8u * (unsigned)bp)) - 1u;
        const int bytepre = (int)(((v & mask) * 0x01010101u) >> 24);
        const int rank = (int)s_dwp[wave][dw] + bytepre + arr1;
        s_m[wave][rank + (b1 >> 5) + 1] = fy;
    }
    const int Fk = (int)s_dwp[wave][8 * lane];       // fines in buckets < 32*lane
    s_m[wave][lane + Fk] = NEAR_F + (float)lane * STEP_F;
    __builtin_amdgcn_wave_barrier();

    // ---- Phase 5: local cleanup (fix within-bucket arrival-order swaps) ----
    {
        const int j = 3 * lane;
        const float t0 = s_m[wave][j], t1 = s_m[wave][j + 1], t2 = s_m[wave][j + 2];
        const float a = fminf(t0, t1), b = fmaxf(t0, t1);
        const float cmin = fminf(b, t2), cmax = fmaxf(b, t2);
        s_m[wave][j]     = fminf(a, cmin);
        s_m[wave][j + 1] = fmaxf(a, cmin);
        s_m[wave][j + 2] = cmax;
    }
    __builtin_amdgcn_wave_barrier();
    if (lane < 63) {
        const int j = 3 * lane + 2;
        const float t0 = s_m[wave][j], t1 = s_m[wave][j + 1];
        s_m[wave][j]     = fminf(t0, t1);
        s_m[wave][j + 1] = fmaxf(t0, t1);
    }
    __builtin_amdgcn_wave_barrier();

    // ---- Phase 6: composite, 4 consecutive samples per lane (lanes 0..47) ----
    float f0 = 1.0f, f1 = 1.0f, f2 = 1.0f, f3 = 1.0f;
    if (lane < 48) {
        const float4 m4 = *(const float4*)&s_m[wave][i0];
        const float mnext = s_m[wave][(lane == 47) ? 191 : (i0 + 4)];
        const float d0 = m4.y - m4.x;
        const float d1 = m4.z - m4.y;
        const float d2 = m4.w - m4.z;
        const float d3 = (lane == 47) ? 1e10f : (mnext - m4.w);
        f0 = 1.0f - (1.0f - __expf(-dv.x * d0)) + 1e-10f;
        f1 = 1.0f - (1.0f - __expf(-dv.y * d1)) + 1e-10f;
        f2 = 1.0f - (1.0f - __expf(-dv.z * d2)) + 1e-10f;
        f3 = 1.0f - (1.0f - __expf(-dv.w * d3)) + 1e-10f;
    }

    float scanp = f0 * f1 * f2 * f3;
    #pragma unroll
    for (int off = 1; off < 64; off <<= 1) {
        const float t = __shfl_up(scanp, off);
        if (lane >= off) scanp *= t;
    }
    float T0 = __shfl_up(scanp, 1);
    if (lane == 0) T0 = 1.0f;
    const float T1 = T0 * f0;
    const float T2 = T1 * f1;
    const float T3 = T2 * f2;

    float ax = 0.f, ay = 0.f, az = 0.f;
    if (lane < 48) {
        const float w0 = T0 * (1.0f - f0 + 1e-10f);
        const float w1 = T1 * (1.0f - f1 + 1e-10f);
        const float w2 = T2 * (1.0f - f2 + 1e-10f);
        const float w3 = T3 * (1.0f - f3 + 1e-10f);
        ax = w0 * c0.x + w1 * c0.w + w2 * c1.z + w3 * c2.y;
        ay = w0 * c0.y + w1 * c1.x + w2 * c1.w + w3 * c2.z;
        az = w0 * c0.z + w1 * c1.y + w2 * c2.x + w3 * c2.w;
    }

    #pragma unroll
    for (int off = 32; off; off >>= 1) {
        ax += __shfl_xor(ax, off);
        ay += __shfl_xor(ay, off);
        az += __shfl_xor(az, off);
    }
    if (lane < 3) {
        const float v = (lane == 0) ? ax : ((lane == 1) ? ay : az);
        out[(size_t)ray * 3 + lane] = v;
    }
}

extern "C" void kernel_launch(void* const* d_in, const int* in_sizes, int n_in,
                              void* d_out, int out_size, void* d_ws, size_t ws_size,
                              hipStream_t stream) {
    // inputs: 0 ray_origin (unused), 1 ray_direction (unused),
    //         2 coarse_depth_values (constant linspace — unused),
    //         3 coarse_weights, 4 u, 5 raw_density, 6 raw_color
    const float* cwts = (const float*)d_in[3];
    const float* u    = (const float*)d_in[4];
    const float* dens = (const float*)d_in[5];
    const float* col  = (const float*)d_in[6];
    float* out = (float*)d_out;

    dim3 grid(B_TOTAL / RPB);
    dim3 block(256);
    hipLaunchKernelGGL(render_ray_kernel, grid, block, 0, stream,
                       cwts, u, dens, col, out);
}